// Round 5
// baseline (170.244 us; speedup 1.0000x reference)
//
#include <hip/hip_runtime.h>

#define NRBF 20
#define FOUT 16
#define NA 768
#define NB 4

// Mapping: thread i owns f-quad (i&3) for m = j*64 + (i>>2); float4 store at
// tileBase + i*16B -> lane-consecutive, perfectly coalesced.
// W for the f-quad lives in 20 float4 registers (80 VGPR); no LDS in hot loop.
// RBF via geometric recurrence (2 exps/m instead of 20):
//   r_0 = e^{-10 d^2}, t_1 = e^{2d-0.1}, r_k = r_{k-1}*t_k, t_{k+1} = t_k*e^{-0.2}.
// Round-4 lesson: unroll-4 on the j-loop -> ~175 VGPR -> 2 waves/SIMD -> dep
// chains uncovered (~55us). Pin unroll(1): ~110 VGPR -> 4 waves/SIMD.

__global__ __launch_bounds__(256) void cfconv_kernel(
    const float* __restrict__ coords,  // [NB, NA, 3] fp32
    const float* __restrict__ Ww,      // [FOUT, NRBF] fp32
    const float* __restrict__ Wb,      // [FOUT] fp32
    float* __restrict__ out)           // [NB, NA, NA, FOUT] fp32
{
    __shared__ float Wt[NRBF * FOUT];      // transposed: Wt[k*16 + f]
    __shared__ float cm[NA * 3];           // all 768 m-coordinates for this batch

    const int tid = threadIdx.x;
    const int n   = blockIdx.x;
    const int b   = blockIdx.y;

    for (int i = tid; i < NRBF * FOUT; i += 256) {
        int k = i >> 4, f = i & 15;
        Wt[i] = Ww[f * NRBF + k];
    }
    const float* cb = coords + (size_t)b * NA * 3;
    for (int i = tid; i < NA * 3; i += 256) cm[i] = cb[i];
    __syncthreads();

    const int fq   = tid & 3;     // f-quad owned by this thread
    const int mloc = tid >> 2;    // m offset within each 64-m tile

    float4 wk[NRBF];
    #pragma unroll
    for (int k = 0; k < NRBF; ++k)
        wk[k] = *reinterpret_cast<const float4*>(&Wt[k * FOUT + 4 * fq]);
    const float4 bias = *reinterpret_cast<const float4*>(Wb + 4 * fq);

    const float xn = cb[n * 3 + 0];
    const float yn = cb[n * 3 + 1];
    const float zn = cb[n * 3 + 2];

    const float u = 0.81873075308f;            // e^{-0.2}
    float* op = out + ((size_t)b * NA + n) * NA * FOUT + tid * 4;

    #pragma unroll 1
    for (int j = 0; j < NA / 64; ++j) {
        const int m = j * 64 + mloc;
        const float dx = xn - cm[m * 3 + 0];
        const float dy = yn - cm[m * 3 + 1];
        const float dz = zn - cm[m * 3 + 2];
        const float d2 = dx * dx + dy * dy + dz * dz;
        const float d  = sqrtf(d2);

        float r = __expf(-10.0f * d2);         // r_0
        float t = __expf(2.0f * d - 0.1f);     // t_1

        float4 a = bias;
        a.x = fmaf(r, wk[0].x, a.x);
        a.y = fmaf(r, wk[0].y, a.y);
        a.z = fmaf(r, wk[0].z, a.z);
        a.w = fmaf(r, wk[0].w, a.w);
        #pragma unroll
        for (int k = 1; k < NRBF; ++k) {
            r *= t;
            t *= u;
            a.x = fmaf(r, wk[k].x, a.x);
            a.y = fmaf(r, wk[k].y, a.y);
            a.z = fmaf(r, wk[k].z, a.z);
            a.w = fmaf(r, wk[k].w, a.w);
        }

        *reinterpret_cast<float4*>(op) = a;
        op += 64 * FOUT;                       // next 64-m tile
    }
}

extern "C" void kernel_launch(void* const* d_in, const int* in_sizes, int n_in,
                              void* d_out, int out_size, void* d_ws, size_t ws_size,
                              hipStream_t stream) {
    const float* coords = (const float*)d_in[0];
    const float* Ww     = (const float*)d_in[1];
    const float* Wb     = (const float*)d_in[2];
    float* out          = (float*)d_out;

    dim3 grid(NA, NB);   // (n, b)
    cfconv_kernel<<<grid, 256, 0, stream>>>(coords, Ww, Wb, out);
}